// Round 8
// baseline (789.938 us; speedup 1.0000x reference)
//
#include <hip/hip_runtime.h>
#include <cstdint>
#include <cstddef>

#define HID 128
#define OUTC 40
#define WTOT 139264  // Wl 49152 | Wr 49152 | W0 8192 | W1 16384 | W2 16384
#define PB 200       // blocks for edge-binning passes
#define NBK_MAX 256  // max buckets (512 nodes each)

typedef __attribute__((ext_vector_type(8))) short short8;
typedef __attribute__((ext_vector_type(4))) float floatx4;

__device__ __forceinline__ unsigned short f2b(float f) {
  unsigned int u = __float_as_uint(f);
  unsigned int r = u + 0x7FFFu + ((u >> 16) & 1u);
  return (unsigned short)(r >> 16);
}
__device__ __forceinline__ float blo(unsigned int u) { return __uint_as_float(u << 16); }
__device__ __forceinline__ float bhi(unsigned int u) { return __uint_as_float(u & 0xFFFF0000u); }
__device__ __forceinline__ unsigned int pack2(float a, float b) {
  return (unsigned int)f2b(a) | ((unsigned int)f2b(b) << 16);
}

__device__ __forceinline__ void async_cp16(const ushort* g, ushort* l) {
  __builtin_amdgcn_global_load_lds((const __attribute__((address_space(1))) void*)g,
                                   (__attribute__((address_space(3))) void*)l, 16, 0, 0);
}

// ---------------- prep kernels ----------------

__global__ void cvt_kernel(const float* __restrict__ in, ushort* __restrict__ out, int n4) {
  int i = blockIdx.x * blockDim.x + threadIdx.x;
  if (i >= n4) return;
  float4 v = ((const float4*)in)[i];
  ushort4 o;
  o.x = f2b(v.x); o.y = f2b(v.y); o.z = f2b(v.z); o.w = f2b(v.w);
  ((ushort4*)out)[i] = o;
}

// all weights + classifier pad + stats init, one launch
__global__ void cvtw_all_kernel(const float* __restrict__ Wl, const float* __restrict__ Wr,
                                const float* __restrict__ W0, const float* __restrict__ W1,
                                const float* __restrict__ W2, const float* __restrict__ Wc,
                                ushort* __restrict__ wb, ushort* __restrict__ wcb,
                                float* __restrict__ stats) {
  int gid = blockIdx.x * blockDim.x + threadIdx.x;
  if (gid < 1024) stats[gid] = 0.0f;
  if (gid < 48 * 64) {  // wcb: 48x256 bf16, rows 40..47 zero
    int row = gid >> 6;
    ushort4 o;
    if (row < 40) {
      float4 v = *(const float4*)(Wc + (size_t)gid * 4);
      o.x = f2b(v.x); o.y = f2b(v.y); o.z = f2b(v.z); o.w = f2b(v.w);
    } else {
      o.x = 0; o.y = 0; o.z = 0; o.w = 0;
    }
    ((ushort4*)wcb)[gid] = o;
  }
  int e4 = gid * 4;
  if (e4 < WTOT) {
    const float* s; int off;
    if (e4 < 49152)       { s = Wl; off = 0; }
    else if (e4 < 98304)  { s = Wr; off = 49152; }
    else if (e4 < 106496) { s = W0; off = 98304; }
    else if (e4 < 122880) { s = W1; off = 106496; }
    else                  { s = W2; off = 122880; }
    float4 v = *(const float4*)(s + (e4 - off));
    ushort4 o;
    o.x = f2b(v.x); o.y = f2b(v.y); o.z = f2b(v.z); o.w = f2b(v.w);
    *(ushort4*)(wb + e4) = o;
  }
}

// alpha -> ab (raw bf16) and anb (normalized bf16), one pass
__global__ void anorm2_kernel(const float* __restrict__ alpha, ushort* __restrict__ ab,
                              ushort* __restrict__ anb, int n) {
  int g = (blockIdx.x * blockDim.x + threadIdx.x) >> 4;  // 16 lanes/node
  int lane = threadIdx.x & 15;
  if (g >= n) return;
  const float4 a = *(const float4*)(alpha + (size_t)g * 64 + lane * 4);
  ushort4 raw;
  raw.x = f2b(a.x); raw.y = f2b(a.y); raw.z = f2b(a.z); raw.w = f2b(a.w);
  *(ushort4*)(ab + (size_t)g * 64 + lane * 4) = raw;
  float d = a.x * a.x + a.y * a.y + a.z * a.z + a.w * a.w;
  d += __shfl_xor(d, 1); d += __shfl_xor(d, 2);
  d += __shfl_xor(d, 4); d += __shfl_xor(d, 8);
  float r = 1.0f / fmaxf(sqrtf(d), 1e-12f);
  ushort4 o;
  o.x = f2b(a.x * r); o.y = f2b(a.y * r); o.z = f2b(a.z * r); o.w = f2b(a.w * r);
  *(ushort4*)(anb + (size_t)g * 64 + lane * 4) = o;
}

// ---------------- exclusive scan (generic, for the bucket table) ----------------

#define SCAN_T 256
#define SCAN_VPT 8
#define SCAN_ELEMS 2048

__global__ void scan1_kernel(const int* __restrict__ cnt, int* __restrict__ outp,
                             int* __restrict__ blksum, int n) {
  __shared__ int sh[SCAN_T];
  int t = threadIdx.x;
  int base = blockIdx.x * SCAN_ELEMS + t * SCAN_VPT;
  int v[SCAN_VPT];
  int s = 0;
#pragma unroll
  for (int i = 0; i < SCAN_VPT; ++i) {
    int idx = base + i;
    v[i] = (idx < n) ? cnt[idx] : 0;
    s += v[i];
  }
  sh[t] = s;
  __syncthreads();
  for (int d = 1; d < SCAN_T; d <<= 1) {
    int add = (t >= d) ? sh[t - d] : 0;
    __syncthreads();
    sh[t] += add;
    __syncthreads();
  }
  int p = sh[t] - s;
#pragma unroll
  for (int i = 0; i < SCAN_VPT; ++i) {
    int idx = base + i;
    if (idx < n) outp[idx] = p;
    p += v[i];
  }
  if (t == SCAN_T - 1) blksum[blockIdx.x] = sh[t];
}

__global__ void scan2_kernel(int* __restrict__ blk, int nb) {
  __shared__ int sh[SCAN_T];
  int t = threadIdx.x;
  int s = (t < nb) ? blk[t] : 0;
  sh[t] = s;
  __syncthreads();
  for (int d = 1; d < SCAN_T; d <<= 1) {
    int add = (t >= d) ? sh[t - d] : 0;
    __syncthreads();
    sh[t] += add;
    __syncthreads();
  }
  if (t < nb) blk[t] = sh[t] - s;
}

__global__ void scan3g_kernel(int* __restrict__ outp, const int* __restrict__ blkoff, int n) {
  int idx = blockIdx.x * blockDim.x + threadIdx.x;
  if (idx < n) outp[idx] += blkoff[idx / SCAN_ELEMS];
}

// ---------------- bucketed CSR build (no global atomics) ----------------

__global__ void binA_kernel(const int* __restrict__ tgt, int* __restrict__ G,
                            int e, int chunk, int nbk) {
  __shared__ int hist[NBK_MAX];
  int tid = threadIdx.x;
  for (int b = tid; b < nbk; b += 256) hist[b] = 0;
  __syncthreads();
  int i0 = blockIdx.x * chunk;
  int i1 = min(e, i0 + chunk);
  for (int j = i0 + tid; j < i1; j += 256) atomicAdd(&hist[tgt[j] >> 9], 1);
  __syncthreads();
  for (int b = tid; b < nbk; b += 256) G[b * PB + blockIdx.x] = hist[b];
}

__global__ void binB_kernel(const int* __restrict__ src, const int* __restrict__ tgt,
                            const int* __restrict__ Gs, int* __restrict__ ebuf,
                            int e, int chunk, int nbk) {
  __shared__ int cur[NBK_MAX];
  int tid = threadIdx.x;
  for (int b = tid; b < nbk; b += 256) cur[b] = Gs[b * PB + blockIdx.x];
  __syncthreads();
  int i0 = blockIdx.x * chunk;
  int i1 = min(e, i0 + chunk);
  for (int j = i0 + tid; j < i1; j += 256) {
    int t = tgt[j];
    int pos = atomicAdd(&cur[t >> 9], 1);
    ebuf[pos] = ((t & 511) << 17) | src[j];
  }
}

__global__ void binC_kernel(const int* __restrict__ ebuf, const int* __restrict__ Gs,
                            int* __restrict__ rowptr, int* __restrict__ csr,
                            int n, int e, int nbk) {
  __shared__ int hist[512];
  __shared__ int scanbuf[256];
  int b = blockIdx.x, tid = threadIdx.x;
  int seg0 = Gs[b * PB];
  int seg1 = (b + 1 < nbk) ? Gs[(b + 1) * PB] : e;
  hist[tid] = 0; hist[tid + 256] = 0;
  __syncthreads();
  for (int j = seg0 + tid; j < seg1; j += 256)
    atomicAdd(&hist[ebuf[j] >> 17], 1);
  __syncthreads();
  int a0 = hist[2 * tid], a1 = hist[2 * tid + 1];
  int s = a0 + a1;
  scanbuf[tid] = s;
  __syncthreads();
  for (int d = 1; d < 256; d <<= 1) {
    int add = (tid >= d) ? scanbuf[tid - d] : 0;
    __syncthreads();
    scanbuf[tid] += add;
    __syncthreads();
  }
  int ex = scanbuf[tid] - s;
  hist[2 * tid] = ex;
  hist[2 * tid + 1] = ex + a0;
  int node0 = b * 512 + 2 * tid;
  if (node0 < n) rowptr[node0] = seg0 + ex;
  if (node0 + 1 < n) rowptr[node0 + 1] = seg0 + ex + a0;
  __syncthreads();
  for (int j = seg0 + tid; j < seg1; j += 256) {
    int val = ebuf[j];
    int pos = atomicAdd(&hist[val >> 17], 1);
    csr[seg0 + pos] = val & 0x1FFFF;
  }
  if (b == nbk - 1 && tid == 0) rowptr[n] = e;
}

// ---------------- gate: pull-based, fused sigmoid (no atomics) ----------------

__global__ void gate_pull_kernel(const ushort* __restrict__ anb, const int* __restrict__ rowptr,
                                 const int* __restrict__ csr, const float* __restrict__ temp,
                                 float* __restrict__ out, int n) {
  int g = (blockIdx.x * blockDim.x + threadIdx.x) >> 3;  // 8 lanes/node
  int lane = threadIdx.x & 7;
  if (g >= n) return;
  uint4 av = *(const uint4*)(anb + (size_t)g * 64 + lane * 8);
  int beg = rowptr[g], end = rowptr[g + 1];
  float acc = 0.f;
  int j = beg;
  for (; j + 1 < end; j += 2) {
    int u0 = csr[j], u1 = csr[j + 1];
    uint4 b0 = *(const uint4*)(anb + (size_t)u0 * 64 + lane * 8);
    uint4 b1 = *(const uint4*)(anb + (size_t)u1 * 64 + lane * 8);
    acc += blo(av.x) * (blo(b0.x) + blo(b1.x)) + bhi(av.x) * (bhi(b0.x) + bhi(b1.x))
         + blo(av.y) * (blo(b0.y) + blo(b1.y)) + bhi(av.y) * (bhi(b0.y) + bhi(b1.y))
         + blo(av.z) * (blo(b0.z) + blo(b1.z)) + bhi(av.z) * (bhi(b0.z) + bhi(b1.z))
         + blo(av.w) * (blo(b0.w) + blo(b1.w)) + bhi(av.w) * (bhi(b0.w) + bhi(b1.w));
  }
  if (j < end) {
    int u0 = csr[j];
    uint4 b0 = *(const uint4*)(anb + (size_t)u0 * 64 + lane * 8);
    acc += blo(av.x) * blo(b0.x) + bhi(av.x) * bhi(b0.x)
         + blo(av.y) * blo(b0.y) + bhi(av.y) * bhi(b0.y)
         + blo(av.z) * blo(b0.z) + bhi(av.z) * bhi(b0.z)
         + blo(av.w) * blo(b0.w) + bhi(av.w) * bhi(b0.w);
  }
  acc += __shfl_xor(acc, 1); acc += __shfl_xor(acc, 2); acc += __shfl_xor(acc, 4);
  if (lane == 0) {
    float m = (1.0f + acc) / (float)(end - beg + 1);  // self-loop dot = 1
    out[g] = 1.0f / (1.0f + expf(-temp[0] * m));
  }
}

// ---------------- MFMA linear (proto branch): C = A@W^T + bias ----------------

template <bool STATS, bool ORELU>
__global__ __launch_bounds__(256) void mlin_kernel(
    const ushort* __restrict__ A1, int K,
    const ushort* __restrict__ W1,
    const float* __restrict__ bias, ushort* __restrict__ C,
    float* __restrict__ stats, int M) {
  __shared__ ushort As[128 * 32];
  __shared__ ushort Bs[128 * 32];
  const int tid = threadIdx.x;
  const int w = tid >> 6, l = tid & 63;
  const int mbase = blockIdx.x * 128;
  const int lm = l & 15, lq = l >> 4;
  floatx4 acc[2][8];
#pragma unroll
  for (int mt = 0; mt < 2; ++mt)
#pragma unroll
    for (int nt = 0; nt < 8; ++nt) {
      floatx4 z = {0.f, 0.f, 0.f, 0.f};
      acc[mt][nt] = z;
    }

  for (int k0 = 0; k0 < K; k0 += 32) {
#pragma unroll
    for (int i = 0; i < 2; ++i) {
      int s = w * 2 + i;
      int rt = s * 16 + (l >> 2);
      int q = (l & 3) ^ ((rt >> 1) & 3);
      int grow = mbase + rt; grow = grow < M ? grow : M - 1;
      async_cp16(A1 + (size_t)grow * K + k0 + q * 8, &As[s * 512]);
      async_cp16(W1 + (size_t)rt * K + k0 + q * 8, &Bs[s * 512]);
    }
    __syncthreads();
    short8 b[8];
#pragma unroll
    for (int nt = 0; nt < 8; ++nt) {
      int row = nt * 16 + lm;
      int q = lq ^ ((row >> 1) & 3);
      b[nt] = *(const short8*)&Bs[row * 32 + q * 8];
    }
#pragma unroll
    for (int mt = 0; mt < 2; ++mt) {
      int row = (w * 2 + mt) * 16 + lm;
      int q = lq ^ ((row >> 1) & 3);
      short8 a = *(const short8*)&As[row * 32 + q * 8];
#pragma unroll
      for (int nt = 0; nt < 8; ++nt)
        acc[mt][nt] = __builtin_amdgcn_mfma_f32_16x16x32_bf16(a, b[nt], acc[mt][nt], 0, 0, 0);
    }
    __syncthreads();
  }

  float ss[8], qq[8];
#pragma unroll
  for (int nt = 0; nt < 8; ++nt) { ss[nt] = 0.f; qq[nt] = 0.f; }
#pragma unroll
  for (int nt = 0; nt < 8; ++nt) {
    int col = nt * 16 + lm;
    float bv = bias[col];
#pragma unroll
    for (int mt = 0; mt < 2; ++mt) {
      int rbase = mbase + (w * 2 + mt) * 16 + lq * 4;
#pragma unroll
      for (int r = 0; r < 4; ++r) {
        int grow = rbase + r;
        if (grow < M) {
          float val = acc[mt][nt][r] + bv;
          if (ORELU) val = fmaxf(val, 0.f);
          C[(size_t)grow * 128 + col] = f2b(val);
          if (STATS) { ss[nt] += val; qq[nt] += val * val; }
        }
      }
    }
  }
  if (STATS) {
    float* sred = (float*)As;
    if (tid < 256) sred[tid] = 0.f;
    __syncthreads();
#pragma unroll
    for (int nt = 0; nt < 8; ++nt) {
      ss[nt] += __shfl_xor(ss[nt], 16); ss[nt] += __shfl_xor(ss[nt], 32);
      qq[nt] += __shfl_xor(qq[nt], 16); qq[nt] += __shfl_xor(qq[nt], 32);
    }
    if (lq == 0) {
#pragma unroll
      for (int nt = 0; nt < 8; ++nt) {
        int col = nt * 16 + lm;
        atomicAdd(&sred[col], ss[nt]);
        atomicAdd(&sred[128 + col], qq[nt]);
      }
    }
    __syncthreads();
    if (tid < 256) atomicAdd(&stats[tid], sred[tid]);
  }
}

// ---------------- fused SAGE layer: gather-mean + MFMA (Wl*agg + Wr*h + b) ----------
// BM=64 rows/block. NOTE: output buffer C must NOT alias input H — phase-1 gathers
// arbitrary rows of H while other blocks' epilogues write C (ping-pong in launcher).

template <bool STATS, bool ORELU>
__global__ __launch_bounds__(256) void smlin_kernel(
    const ushort* __restrict__ H, const int* __restrict__ rowptr,
    const int* __restrict__ csr, const ushort* __restrict__ Wl,
    const ushort* __restrict__ Wr, const float* __restrict__ bias,
    ushort* __restrict__ C, float* __restrict__ stats, int M) {
  __shared__ ushort aggT[64 * 128];  // 16KB; reused as As2 (part1) and sred (epilogue)
  __shared__ ushort Bs[128 * 32];    // 8KB
  const int tid = threadIdx.x;
  const int w = tid >> 6, l = tid & 63;
  const int mbase = blockIdx.x * 64;
  const int lm = l & 15, lq = l >> 4;

  // ---- phase 1: gather ----
  {
    const int grp = tid >> 4;   // 0..15
    const int ch = tid & 15;    // 16B chunk index = elements ch*8..ch*8+7
    for (int rr = 0; rr < 4; ++rr) {
      const int rt = grp * 4 + rr;
      const int grow = mbase + rt;
      float a0=0,a1=0,a2=0,a3=0,a4=0,a5=0,a6=0,a7=0;
      float r = 0.f;
      if (grow < M) {
        const int beg = rowptr[grow], end = rowptr[grow + 1];
        int j = beg;
        for (; j + 3 < end; j += 4) {
          int u0 = csr[j], u1 = csr[j + 1], u2 = csr[j + 2], u3 = csr[j + 3];
          uint4 v0 = *(const uint4*)(H + (size_t)u0 * HID + ch * 8);
          uint4 v1 = *(const uint4*)(H + (size_t)u1 * HID + ch * 8);
          uint4 v2 = *(const uint4*)(H + (size_t)u2 * HID + ch * 8);
          uint4 v3 = *(const uint4*)(H + (size_t)u3 * HID + ch * 8);
          a0 += (blo(v0.x) + blo(v1.x)) + (blo(v2.x) + blo(v3.x));
          a1 += (bhi(v0.x) + bhi(v1.x)) + (bhi(v2.x) + bhi(v3.x));
          a2 += (blo(v0.y) + blo(v1.y)) + (blo(v2.y) + blo(v3.y));
          a3 += (bhi(v0.y) + bhi(v1.y)) + (bhi(v2.y) + bhi(v3.y));
          a4 += (blo(v0.z) + blo(v1.z)) + (blo(v2.z) + blo(v3.z));
          a5 += (bhi(v0.z) + bhi(v1.z)) + (bhi(v2.z) + bhi(v3.z));
          a6 += (blo(v0.w) + blo(v1.w)) + (blo(v2.w) + blo(v3.w));
          a7 += (bhi(v0.w) + bhi(v1.w)) + (bhi(v2.w) + bhi(v3.w));
        }
        for (; j < end; ++j) {
          int u0 = csr[j];
          uint4 v0 = *(const uint4*)(H + (size_t)u0 * HID + ch * 8);
          a0 += blo(v0.x); a1 += bhi(v0.x); a2 += blo(v0.y); a3 += bhi(v0.y);
          a4 += blo(v0.z); a5 += bhi(v0.z); a6 += blo(v0.w); a7 += bhi(v0.w);
        }
        r = (end > beg) ? 1.0f / (float)(end - beg) : 0.0f;
      }
      uint4 o;
      o.x = pack2(a0 * r, a1 * r); o.y = pack2(a2 * r, a3 * r);
      o.z = pack2(a4 * r, a5 * r); o.w = pack2(a6 * r, a7 * r);
      *(uint4*)&aggT[rt * 128 + ((ch ^ (rt & 15)) << 3)] = o;
    }
  }
  __syncthreads();

  floatx4 acc[8];
#pragma unroll
  for (int nt = 0; nt < 8; ++nt) {
    floatx4 z = {0.f, 0.f, 0.f, 0.f};
    acc[nt] = z;
  }
  const int arow = w * 16 + lm;  // this lane's A row (wave w owns m-tile w)

  // ---- part 0: Wl * agg (A from aggT) ----
  for (int k0 = 0; k0 < 128; k0 += 32) {
#pragma unroll
    for (int i = 0; i < 2; ++i) {
      int s = w * 2 + i;
      int rt = s * 16 + (l >> 2);
      int q = (l & 3) ^ ((rt >> 1) & 3);
      async_cp16(Wl + (size_t)rt * 128 + k0 + q * 8, &Bs[s * 512]);
    }
    __syncthreads();
    short8 a = *(const short8*)&aggT[arow * 128 + ((((k0 >> 3) + lq) ^ (arow & 15)) << 3)];
#pragma unroll
    for (int nt = 0; nt < 8; ++nt) {
      int row = nt * 16 + lm;
      int q = lq ^ ((row >> 1) & 3);
      short8 b = *(const short8*)&Bs[row * 32 + q * 8];
      acc[nt] = __builtin_amdgcn_mfma_f32_16x16x32_bf16(a, b, acc[nt], 0, 0, 0);
    }
    __syncthreads();
  }

  // ---- part 1: Wr * h (A staged into aggT[0:4KB]) ----
  ushort* As2 = aggT;
  for (int k0 = 0; k0 < 128; k0 += 32) {
    {
      int rt = w * 16 + (l >> 2);
      int q = (l & 3) ^ ((rt >> 1) & 3);
      int grow = mbase + rt; grow = grow < M ? grow : M - 1;
      async_cp16(H + (size_t)grow * 128 + k0 + q * 8, &As2[w * 512]);
#pragma unroll
      for (int i = 0; i < 2; ++i) {
        int s = w * 2 + i;
        int rt2 = s * 16 + (l >> 2);
        int q2 = (l & 3) ^ ((rt2 >> 1) & 3);
        async_cp16(Wr + (size_t)rt2 * 128 + k0 + q2 * 8, &Bs[s * 512]);
      }
    }
    __syncthreads();
    short8 a = *(const short8*)&As2[arow * 32 + (lq ^ ((arow >> 1) & 3)) * 8];
#pragma unroll
    for (int nt = 0; nt < 8; ++nt) {
      int row = nt * 16 + lm;
      int q = lq ^ ((row >> 1) & 3);
      short8 b = *(const short8*)&Bs[row * 32 + q * 8];
      acc[nt] = __builtin_amdgcn_mfma_f32_16x16x32_bf16(a, b, acc[nt], 0, 0, 0);
    }
    __syncthreads();
  }

  // ---- epilogue ----
  float ss[8], qq[8];
#pragma unroll
  for (int nt = 0; nt < 8; ++nt) { ss[nt] = 0.f; qq[nt] = 0.f; }
#pragma unroll
  for (int nt = 0; nt < 8; ++nt) {
    int col = nt * 16 + lm;
    float bv = bias[col];
    int rbase = mbase + w * 16 + lq * 4;
#pragma unroll
    for (int r = 0; r < 4; ++r) {
      int grow = rbase + r;
      if (grow < M) {
        float val = acc[nt][r] + bv;
        if (ORELU) val = fmaxf(val, 0.f);
        C[(size_t)grow * 128 + col] = f2b(val);
        if (STATS) { ss[nt] += val; qq[nt] += val * val; }
      }
    }
  }
  if (STATS) {
    float* sred = (float*)aggT;  // dead after part1's final barrier
    if (tid < 256) sred[tid] = 0.f;
    __syncthreads();
#pragma unroll
    for (int nt = 0; nt < 8; ++nt) {
      ss[nt] += __shfl_xor(ss[nt], 16); ss[nt] += __shfl_xor(ss[nt], 32);
      qq[nt] += __shfl_xor(qq[nt], 16); qq[nt] += __shfl_xor(qq[nt], 32);
    }
    if (lq == 0) {
#pragma unroll
      for (int nt = 0; nt < 8; ++nt) {
        int col = nt * 16 + lm;
        atomicAdd(&sred[col], ss[nt]);
        atomicAdd(&sred[128 + col], qq[nt]);
      }
    }
    __syncthreads();
    if (tid < 256) atomicAdd(&stats[tid], sred[tid]);
  }
}

// ---------------- BatchNorm apply (bf16 in-place, latency-optimized) ----------------

template <int ACT>  // 0=relu, 1=sigmoid
__global__ __launch_bounds__(256) void bnb_kernel(
    ushort* __restrict__ buf, const float* __restrict__ stats,
    const float* __restrict__ gamma, const float* __restrict__ beta, int n) {
  const int S = gridDim.x * 256;  // multiple of 16
  int idx = blockIdx.x * 256 + threadIdx.x;
  const int c0 = (idx & 15) * 8;
  const float inv_n = 1.0f / (float)n;
  float sc[8], sh[8];
#pragma unroll
  for (int d = 0; d < 8; ++d) {
    int c = c0 + d;
    float mu = stats[c] * inv_n;
    float var = stats[128 + c] * inv_n - mu * mu;
    float s = rsqrtf(var + 1e-5f) * gamma[c];
    sc[d] = s;
    sh[d] = beta[c] - mu * s;
  }
  const int n16 = n * 16;
  for (; idx < n16; idx += S) {
    uint4 v = ((const uint4*)buf)[idx];
    float x[8] = {blo(v.x), bhi(v.x), blo(v.y), bhi(v.y),
                  blo(v.z), bhi(v.z), blo(v.w), bhi(v.w)};
#pragma unroll
    for (int d = 0; d < 8; ++d) {
      float y = x[d] * sc[d] + sh[d];
      x[d] = (ACT == 0) ? fmaxf(y, 0.f) : 1.0f / (1.0f + expf(-y));
    }
    uint4 o;
    o.x = pack2(x[0], x[1]); o.y = pack2(x[2], x[3]);
    o.z = pack2(x[4], x[5]); o.w = pack2(x[6], x[7]);
    ((uint4*)buf)[idx] = o;
  }
}

// ---------------- classifier: MFMA GEMM + fused log_softmax ----------------

__global__ __launch_bounds__(256) void clsm_kernel(
    const ushort* __restrict__ A1, const ushort* __restrict__ A2,
    const ushort* __restrict__ Wcb, const float* __restrict__ bias,
    float* __restrict__ C, int M) {
  __shared__ ushort As[128 * 32];
  __shared__ ushort Bs[48 * 32];
  const int tid = threadIdx.x;
  const int w = tid >> 6, l = tid & 63;
  const int mbase = blockIdx.x * 128;
  const int lm = l & 15, lq = l >> 4;
  floatx4 acc[2][3];
#pragma unroll
  for (int mt = 0; mt < 2; ++mt)
#pragma unroll
    for (int nt = 0; nt < 3; ++nt) {
      floatx4 z = {0.f, 0.f, 0.f, 0.f};
      acc[mt][nt] = z;
    }

  for (int part = 0; part < 2; ++part) {
    const ushort* Ap = part ? A2 : A1;
    for (int k0 = 0; k0 < 128; k0 += 32) {
#pragma unroll
      for (int i = 0; i < 2; ++i) {
        int s = w * 2 + i;
        int rt = s * 16 + (l >> 2);
        int q = (l & 3) ^ ((rt >> 1) & 3);
        int grow = mbase + rt; grow = grow < M ? grow : M - 1;
        async_cp16(Ap + (size_t)grow * 128 + k0 + q * 8, &As[s * 512]);
      }
      if (w < 3) {
        int rt = w * 16 + (l >> 2);
        int q = (l & 3) ^ ((rt >> 1) & 3);
        async_cp16(Wcb + (size_t)rt * 256 + part * 128 + k0 + q * 8, &Bs[w * 512]);
      }
      __syncthreads();
      short8 b[3];
#pragma unroll
      for (int nt = 0; nt < 3; ++nt) {
        int row = nt * 16 + lm;
        int q = lq ^ ((row >> 1) & 3);
        b[nt] = *(const short8*)&Bs[row * 32 + q * 8];
      }
#pragma unroll
      for (int mt = 0; mt < 2; ++mt) {
        int row = (w * 2 + mt) * 16 + lm;
        int q = lq ^ ((row >> 1) & 3);
        short8 a = *(const short8*)&As[row * 32 + q * 8];
#pragma unroll
        for (int nt = 0; nt < 3; ++nt)
          acc[mt][nt] = __builtin_amdgcn_mfma_f32_16x16x32_bf16(a, b[nt], acc[mt][nt], 0, 0, 0);
      }
      __syncthreads();
    }
  }

  float b0v = bias[lm], b1v = bias[lm + 16];
  float b2v = (lm < 8) ? bias[lm + 32] : 0.f;
#pragma unroll
  for (int mt = 0; mt < 2; ++mt) {
#pragma unroll
    for (int r = 0; r < 4; ++r) {
      int grow = mbase + (w * 2 + mt) * 16 + lq * 4 + r;
      float v0 = acc[mt][0][r] + b0v;
      float v1 = acc[mt][1][r] + b1v;
      float v2 = (lm < 8) ? acc[mt][2][r] + b2v : -3.4e38f;
      float m = fmaxf(fmaxf(v0, v1), v2);
      m = fmaxf(m, __shfl_xor(m, 1)); m = fmaxf(m, __shfl_xor(m, 2));
      m = fmaxf(m, __shfl_xor(m, 4)); m = fmaxf(m, __shfl_xor(m, 8));
      float s = expf(v0 - m) + expf(v1 - m) + ((lm < 8) ? expf(v2 - m) : 0.f);
      s += __shfl_xor(s, 1); s += __shfl_xor(s, 2);
      s += __shfl_xor(s, 4); s += __shfl_xor(s, 8);
      float ls = m + logf(s);
      if (grow < M) {
        C[(size_t)grow * OUTC + lm] = v0 - ls;
        C[(size_t)grow * OUTC + lm + 16] = v1 - ls;
        if (lm < 8) C[(size_t)grow * OUTC + lm + 32] = v2 - ls;
      }
    }
  }
}

// ---------------- launch ----------------

extern "C" void kernel_launch(void* const* d_in, const int* in_sizes, int n_in,
                              void* d_out, int out_size, void* d_ws, size_t ws_size,
                              hipStream_t stream) {
  const float* x       = (const float*)d_in[0];
  const float* alpha   = (const float*)d_in[1];
  const int*   eidx    = (const int*)d_in[2];
  const float* sage_Wl = (const float*)d_in[3];
  const float* sage_bl = (const float*)d_in[4];
  const float* sage_Wr = (const float*)d_in[5];
  const float* sage_g  = (const float*)d_in[6];
  const float* sage_b  = (const float*)d_in[7];
  const float* W0 = (const float*)d_in[8];
  const float* b0 = (const float*)d_in[9];
  const float* W1 = (const float*)d_in[10];
  const float* b1 = (const float*)d_in[11];
  const float* W2 = (const float*)d_in[12];
  const float* b2 = (const float*)d_in[13];
  const float* mg = (const float*)d_in[14];
  const float* mb = (const float*)d_in[15];
  const float* Wc = (const float*)d_in[16];
  const float* bc = (const float*)d_in[17];
  const float* temp = (const float*)d_in[18];
  float* out = (float*)d_out;

  const int n = in_sizes[0] / HID;  // 100000
  const int e = in_sizes[2] / 2;    // 1600000
  const int* src = eidx;
  const int* tgt = eidx + e;

  const int nbk = (n + 511) >> 9;
  const int glen = nbk * PB;
  const int chunk = (e + PB - 1) / PB;

  // workspace layout (bf16 buffers first: 16B aligned)
  char* p = (char*)d_ws;
  ushort* xb     = (ushort*)p; p += (size_t)n * HID * 2;   // alias: hgnn (SAGE L2 out)
  ushort* hb     = (ushort*)p; p += (size_t)n * HID * 2;   // alias: anb; SAGE L0 out
  ushort* ab     = (ushort*)p; p += (size_t)n * HID * 2;   // alpha bf16; SAGE L1 out
  ushort* hproto = (ushort*)p; p += (size_t)n * HID * 2;   // alias: ebuf
  ushort* wb     = (ushort*)p; p += (size_t)WTOT * 2;
  ushort* wcb    = (ushort*)p; p += (size_t)48 * 256 * 2;
  float* stats = (float*)p; p += 1024 * 4;
  int* rowptr = (int*)p; p += ((size_t)n + 1) * 4;
  int* csr    = (int*)p; p += (size_t)e * 4;
  int* G      = (int*)p; p += (size_t)glen * 4;
  int* Gs     = (int*)p; p += (size_t)glen * 4;
  int* blks   = (int*)p;
  ushort* hgnn = xb;
  ushort* anb  = hb;
  int*    ebuf = (int*)hproto;
  ushort* Wlb = wb, *Wrb = wb + 49152, *W0b = wb + 98304, *W1b = wb + 106496, *W2b = wb + 122880;

  const int T = 256;
  const int nb_scan = (glen + SCAN_ELEMS - 1) / SCAN_ELEMS;

  // ---- prep ----
  cvt_kernel<<<(n * (HID / 4) + T - 1) / T, T, 0, stream>>>(x, xb, n * (HID / 4));
  anorm2_kernel<<<(int)(((size_t)n * 16 + T - 1) / T), T, 0, stream>>>(alpha, ab, anb, n);
  cvtw_all_kernel<<<(WTOT / 4 + T - 1) / T, T, 0, stream>>>(sage_Wl, sage_Wr, W0, W1, W2, Wc,
                                                            wb, wcb, stats);

  // ---- bucketed CSR build ----
  binA_kernel<<<PB, T, 0, stream>>>(tgt, G, e, chunk, nbk);
  scan1_kernel<<<nb_scan, SCAN_T, 0, stream>>>(G, Gs, blks, glen);
  scan2_kernel<<<1, SCAN_T, 0, stream>>>(blks, nb_scan);
  scan3g_kernel<<<(glen + T - 1) / T, T, 0, stream>>>(Gs, blks, glen);
  binB_kernel<<<PB, T, 0, stream>>>(src, tgt, Gs, ebuf, e, chunk, nbk);
  binC_kernel<<<nbk, T, 0, stream>>>(ebuf, Gs, rowptr, csr, n, e, nbk);

  // ---- gate (pull, fused sigmoid) ----
  gate_pull_kernel<<<(int)(((size_t)n * 8 + T - 1) / T), T, 0, stream>>>(
      anb, rowptr, csr, temp, out + (size_t)n * OUTC, n);

  const int gLin = (n + 127) / 128;
  const int gSag = (n + 63) / 64;
  const int gBn = 1024;

  // ---- Proto MLP (hb free after gate_pull consumed anb) ----
  mlin_kernel<true, false><<<gLin, T, 0, stream>>>(ab, 64, W0b, b0, hb, stats + 512, n);
  bnb_kernel<1><<<gBn, T, 0, stream>>>(hb, stats + 512, mg, mb, n);
  mlin_kernel<true, false><<<gLin, T, 0, stream>>>(hb, 128, W1b, b1, hb, stats + 768, n);
  bnb_kernel<1><<<gBn, T, 0, stream>>>(hb, stats + 768, mg + HID, mb + HID, n);
  mlin_kernel<false, true><<<gLin, T, 0, stream>>>(hb, 128, W2b, b2, hproto, nullptr, n);

  // ---- SAGE (fused aggregate+GEMM; ping-pong xb -> hb -> ab -> xb) ----
  smlin_kernel<true, false><<<gSag, T, 0, stream>>>(xb, rowptr, csr, Wlb, Wrb,
                                                    sage_bl, hb, stats + 0, n);
  bnb_kernel<0><<<gBn, T, 0, stream>>>(hb, stats + 0, sage_g, sage_b, n);
  smlin_kernel<true, false><<<gSag, T, 0, stream>>>(hb, rowptr, csr, Wlb + 16384, Wrb + 16384,
                                                    sage_bl + HID, ab, stats + 256, n);
  bnb_kernel<0><<<gBn, T, 0, stream>>>(ab, stats + 256, sage_g + HID, sage_b + HID, n);
  smlin_kernel<false, true><<<gSag, T, 0, stream>>>(ab, rowptr, csr, Wlb + 32768, Wrb + 32768,
                                                    sage_bl + 2 * HID, hgnn, nullptr, n);

  // ---- classifier (MFMA, log_softmax fused) ----
  clsm_kernel<<<gLin, T, 0, stream>>>(hgnn, hproto, wcb, bc, out, n);
}

// Round 9
// 765.895 us; speedup vs baseline: 1.0314x; 1.0314x over previous
//
#include <hip/hip_runtime.h>
#include <cstdint>
#include <cstddef>

#define HID 128
#define OUTC 40
#define WTOT 139264  // Wl 49152 | Wr 49152 | W0 8192 | W1 16384 | W2 16384
#define PB 200       // blocks for edge-binning passes
#define NBK_MAX 256  // max buckets (512 nodes each)

typedef __attribute__((ext_vector_type(8))) short short8;
typedef __attribute__((ext_vector_type(4))) float floatx4;

__device__ __forceinline__ unsigned short f2b(float f) {
  unsigned int u = __float_as_uint(f);
  unsigned int r = u + 0x7FFFu + ((u >> 16) & 1u);
  return (unsigned short)(r >> 16);
}
__device__ __forceinline__ float blo(unsigned int u) { return __uint_as_float(u << 16); }
__device__ __forceinline__ float bhi(unsigned int u) { return __uint_as_float(u & 0xFFFF0000u); }
__device__ __forceinline__ unsigned int pack2(float a, float b) {
  return (unsigned int)f2b(a) | ((unsigned int)f2b(b) << 16);
}

__device__ __forceinline__ void async_cp16(const ushort* g, ushort* l) {
  __builtin_amdgcn_global_load_lds((const __attribute__((address_space(1))) void*)g,
                                   (__attribute__((address_space(3))) void*)l, 16, 0, 0);
}

// ---------------- prep kernels ----------------

__global__ void cvt_kernel(const float* __restrict__ in, ushort* __restrict__ out, int n4) {
  int i = blockIdx.x * blockDim.x + threadIdx.x;
  if (i >= n4) return;
  float4 v = ((const float4*)in)[i];
  ushort4 o;
  o.x = f2b(v.x); o.y = f2b(v.y); o.z = f2b(v.z); o.w = f2b(v.w);
  ((ushort4*)out)[i] = o;
}

// all weights + classifier pad + stats init, one launch
__global__ void cvtw_all_kernel(const float* __restrict__ Wl, const float* __restrict__ Wr,
                                const float* __restrict__ W0, const float* __restrict__ W1,
                                const float* __restrict__ W2, const float* __restrict__ Wc,
                                ushort* __restrict__ wb, ushort* __restrict__ wcb,
                                float* __restrict__ stats) {
  int gid = blockIdx.x * blockDim.x + threadIdx.x;
  if (gid < 1024) stats[gid] = 0.0f;
  if (gid < 48 * 64) {  // wcb: 48x256 bf16, rows 40..47 zero
    int row = gid >> 6;
    ushort4 o;
    if (row < 40) {
      float4 v = *(const float4*)(Wc + (size_t)gid * 4);
      o.x = f2b(v.x); o.y = f2b(v.y); o.z = f2b(v.z); o.w = f2b(v.w);
    } else {
      o.x = 0; o.y = 0; o.z = 0; o.w = 0;
    }
    ((ushort4*)wcb)[gid] = o;
  }
  int e4 = gid * 4;
  if (e4 < WTOT) {
    const float* s; int off;
    if (e4 < 49152)       { s = Wl; off = 0; }
    else if (e4 < 98304)  { s = Wr; off = 49152; }
    else if (e4 < 106496) { s = W0; off = 98304; }
    else if (e4 < 122880) { s = W1; off = 106496; }
    else                  { s = W2; off = 122880; }
    float4 v = *(const float4*)(s + (e4 - off));
    ushort4 o;
    o.x = f2b(v.x); o.y = f2b(v.y); o.z = f2b(v.z); o.w = f2b(v.w);
    *(ushort4*)(wb + e4) = o;
  }
}

// alpha -> ab (raw bf16) and anb (normalized bf16), one pass
__global__ void anorm2_kernel(const float* __restrict__ alpha, ushort* __restrict__ ab,
                              ushort* __restrict__ anb, int n) {
  int g = (blockIdx.x * blockDim.x + threadIdx.x) >> 4;  // 16 lanes/node
  int lane = threadIdx.x & 15;
  if (g >= n) return;
  const float4 a = *(const float4*)(alpha + (size_t)g * 64 + lane * 4);
  ushort4 raw;
  raw.x = f2b(a.x); raw.y = f2b(a.y); raw.z = f2b(a.z); raw.w = f2b(a.w);
  *(ushort4*)(ab + (size_t)g * 64 + lane * 4) = raw;
  float d = a.x * a.x + a.y * a.y + a.z * a.z + a.w * a.w;
  d += __shfl_xor(d, 1); d += __shfl_xor(d, 2);
  d += __shfl_xor(d, 4); d += __shfl_xor(d, 8);
  float r = 1.0f / fmaxf(sqrtf(d), 1e-12f);
  ushort4 o;
  o.x = f2b(a.x * r); o.y = f2b(a.y * r); o.z = f2b(a.z * r); o.w = f2b(a.w * r);
  *(ushort4*)(anb + (size_t)g * 64 + lane * 4) = o;
}

// ---------------- exclusive scan (generic, for the bucket table) ----------------

#define SCAN_T 256
#define SCAN_VPT 8
#define SCAN_ELEMS 2048

__global__ void scan1_kernel(const int* __restrict__ cnt, int* __restrict__ outp,
                             int* __restrict__ blksum, int n) {
  __shared__ int sh[SCAN_T];
  int t = threadIdx.x;
  int base = blockIdx.x * SCAN_ELEMS + t * SCAN_VPT;
  int v[SCAN_VPT];
  int s = 0;
#pragma unroll
  for (int i = 0; i < SCAN_VPT; ++i) {
    int idx = base + i;
    v[i] = (idx < n) ? cnt[idx] : 0;
    s += v[i];
  }
  sh[t] = s;
  __syncthreads();
  for (int d = 1; d < SCAN_T; d <<= 1) {
    int add = (t >= d) ? sh[t - d] : 0;
    __syncthreads();
    sh[t] += add;
    __syncthreads();
  }
  int p = sh[t] - s;
#pragma unroll
  for (int i = 0; i < SCAN_VPT; ++i) {
    int idx = base + i;
    if (idx < n) outp[idx] = p;
    p += v[i];
  }
  if (t == SCAN_T - 1) blksum[blockIdx.x] = sh[t];
}

__global__ void scan2_kernel(int* __restrict__ blk, int nb) {
  __shared__ int sh[SCAN_T];
  int t = threadIdx.x;
  int s = (t < nb) ? blk[t] : 0;
  sh[t] = s;
  __syncthreads();
  for (int d = 1; d < SCAN_T; d <<= 1) {
    int add = (t >= d) ? sh[t - d] : 0;
    __syncthreads();
    sh[t] += add;
    __syncthreads();
  }
  if (t < nb) blk[t] = sh[t] - s;
}

__global__ void scan3g_kernel(int* __restrict__ outp, const int* __restrict__ blkoff, int n) {
  int idx = blockIdx.x * blockDim.x + threadIdx.x;
  if (idx < n) outp[idx] += blkoff[idx / SCAN_ELEMS];
}

// ---------------- bucketed CSR build (no global atomics) ----------------

__global__ void binA_kernel(const int* __restrict__ tgt, int* __restrict__ G,
                            int e, int chunk, int nbk) {
  __shared__ int hist[NBK_MAX];
  int tid = threadIdx.x;
  for (int b = tid; b < nbk; b += 256) hist[b] = 0;
  __syncthreads();
  int i0 = blockIdx.x * chunk;
  int i1 = min(e, i0 + chunk);
  for (int j = i0 + tid; j < i1; j += 256) atomicAdd(&hist[tgt[j] >> 9], 1);
  __syncthreads();
  for (int b = tid; b < nbk; b += 256) G[b * PB + blockIdx.x] = hist[b];
}

__global__ void binB_kernel(const int* __restrict__ src, const int* __restrict__ tgt,
                            const int* __restrict__ Gs, int* __restrict__ ebuf,
                            int e, int chunk, int nbk) {
  __shared__ int cur[NBK_MAX];
  int tid = threadIdx.x;
  for (int b = tid; b < nbk; b += 256) cur[b] = Gs[b * PB + blockIdx.x];
  __syncthreads();
  int i0 = blockIdx.x * chunk;
  int i1 = min(e, i0 + chunk);
  for (int j = i0 + tid; j < i1; j += 256) {
    int t = tgt[j];
    int pos = atomicAdd(&cur[t >> 9], 1);
    ebuf[pos] = ((t & 511) << 17) | src[j];
  }
}

__global__ void binC_kernel(const int* __restrict__ ebuf, const int* __restrict__ Gs,
                            int* __restrict__ rowptr, int* __restrict__ csr,
                            int n, int e, int nbk) {
  __shared__ int hist[512];
  __shared__ int scanbuf[256];
  int b = blockIdx.x, tid = threadIdx.x;
  int seg0 = Gs[b * PB];
  int seg1 = (b + 1 < nbk) ? Gs[(b + 1) * PB] : e;
  hist[tid] = 0; hist[tid + 256] = 0;
  __syncthreads();
  for (int j = seg0 + tid; j < seg1; j += 256)
    atomicAdd(&hist[ebuf[j] >> 17], 1);
  __syncthreads();
  int a0 = hist[2 * tid], a1 = hist[2 * tid + 1];
  int s = a0 + a1;
  scanbuf[tid] = s;
  __syncthreads();
  for (int d = 1; d < 256; d <<= 1) {
    int add = (tid >= d) ? scanbuf[tid - d] : 0;
    __syncthreads();
    scanbuf[tid] += add;
    __syncthreads();
  }
  int ex = scanbuf[tid] - s;
  hist[2 * tid] = ex;
  hist[2 * tid + 1] = ex + a0;
  int node0 = b * 512 + 2 * tid;
  if (node0 < n) rowptr[node0] = seg0 + ex;
  if (node0 + 1 < n) rowptr[node0 + 1] = seg0 + ex + a0;
  __syncthreads();
  for (int j = seg0 + tid; j < seg1; j += 256) {
    int val = ebuf[j];
    int pos = atomicAdd(&hist[val >> 17], 1);
    csr[seg0 + pos] = val & 0x1FFFF;
  }
  if (b == nbk - 1 && tid == 0) rowptr[n] = e;
}

// ---------------- fused layer-0 aggregate + gate ----------------
// 16 lanes/node. Per neighbor u: lanes gather the h-row (16B chunks) for the mean
// AND an 8B chunk of the normalized-alpha row for the gate dot. Self-loop dot = 1.

__global__ void agg_gate_kernel(const ushort* __restrict__ h, const ushort* __restrict__ anb,
                                const int* __restrict__ rowptr, const int* __restrict__ csr,
                                const float* __restrict__ temp, float* __restrict__ gout,
                                ushort* __restrict__ outb, int n) {
  int g = (blockIdx.x * blockDim.x + threadIdx.x) >> 4;  // 16 lanes/node
  int lane = threadIdx.x & 15;
  if (g >= n) return;
  int beg = rowptr[g], end = rowptr[g + 1];
  // this node's normalized-alpha chunk (4 bf16 = 8B per lane)
  uint2 av = *(const uint2*)(anb + (size_t)g * 64 + lane * 4);
  float av0 = blo(av.x), av1 = bhi(av.x), av2 = blo(av.y), av3 = bhi(av.y);
  float a0=0,a1=0,a2=0,a3=0,a4=0,a5=0,a6=0,a7=0;
  float dot = 0.f;
  int j = beg;
  for (; j + 3 < end; j += 4) {
    int u0 = csr[j], u1 = csr[j + 1], u2 = csr[j + 2], u3 = csr[j + 3];
    uint4 v0 = *(const uint4*)(h + (size_t)u0 * HID + lane * 8);
    uint4 v1 = *(const uint4*)(h + (size_t)u1 * HID + lane * 8);
    uint4 v2 = *(const uint4*)(h + (size_t)u2 * HID + lane * 8);
    uint4 v3 = *(const uint4*)(h + (size_t)u3 * HID + lane * 8);
    uint2 w0 = *(const uint2*)(anb + (size_t)u0 * 64 + lane * 4);
    uint2 w1 = *(const uint2*)(anb + (size_t)u1 * 64 + lane * 4);
    uint2 w2 = *(const uint2*)(anb + (size_t)u2 * 64 + lane * 4);
    uint2 w3 = *(const uint2*)(anb + (size_t)u3 * 64 + lane * 4);
    a0 += (blo(v0.x) + blo(v1.x)) + (blo(v2.x) + blo(v3.x));
    a1 += (bhi(v0.x) + bhi(v1.x)) + (bhi(v2.x) + bhi(v3.x));
    a2 += (blo(v0.y) + blo(v1.y)) + (blo(v2.y) + blo(v3.y));
    a3 += (bhi(v0.y) + bhi(v1.y)) + (bhi(v2.y) + bhi(v3.y));
    a4 += (blo(v0.z) + blo(v1.z)) + (blo(v2.z) + blo(v3.z));
    a5 += (bhi(v0.z) + bhi(v1.z)) + (bhi(v2.z) + bhi(v3.z));
    a6 += (blo(v0.w) + blo(v1.w)) + (blo(v2.w) + blo(v3.w));
    a7 += (bhi(v0.w) + bhi(v1.w)) + (bhi(v2.w) + bhi(v3.w));
    dot += av0 * (blo(w0.x) + blo(w1.x) + blo(w2.x) + blo(w3.x))
         + av1 * (bhi(w0.x) + bhi(w1.x) + bhi(w2.x) + bhi(w3.x))
         + av2 * (blo(w0.y) + blo(w1.y) + blo(w2.y) + blo(w3.y))
         + av3 * (bhi(w0.y) + bhi(w1.y) + bhi(w2.y) + bhi(w3.y));
  }
  for (; j < end; ++j) {
    int u0 = csr[j];
    uint4 v0 = *(const uint4*)(h + (size_t)u0 * HID + lane * 8);
    uint2 w0 = *(const uint2*)(anb + (size_t)u0 * 64 + lane * 4);
    a0 += blo(v0.x); a1 += bhi(v0.x); a2 += blo(v0.y); a3 += bhi(v0.y);
    a4 += blo(v0.z); a5 += bhi(v0.z); a6 += blo(v0.w); a7 += bhi(v0.w);
    dot += av0 * blo(w0.x) + av1 * bhi(w0.x) + av2 * blo(w0.y) + av3 * bhi(w0.y);
  }
  float r = (end > beg) ? 1.0f / (float)(end - beg) : 0.0f;
  uint4 o;
  o.x = pack2(a0 * r, a1 * r); o.y = pack2(a2 * r, a3 * r);
  o.z = pack2(a4 * r, a5 * r); o.w = pack2(a6 * r, a7 * r);
  *(uint4*)(outb + (size_t)g * HID + lane * 8) = o;
  dot += __shfl_xor(dot, 1); dot += __shfl_xor(dot, 2);
  dot += __shfl_xor(dot, 4); dot += __shfl_xor(dot, 8);
  if (lane == 0) {
    float m = (1.0f + dot) / (float)(end - beg + 1);  // self-loop dot = 1
    gout[g] = 1.0f / (1.0f + expf(-temp[0] * m));
  }
}

// ---------------- SAGE mean aggregation (bf16 in/out, f32 accumulate) ----------------

__global__ void agg_b_kernel(const ushort* __restrict__ h, const int* __restrict__ rowptr,
                             const int* __restrict__ csr, ushort* __restrict__ outb, int n) {
  int g = (blockIdx.x * blockDim.x + threadIdx.x) >> 4;  // 16 lanes / node
  int lane = threadIdx.x & 15;
  if (g >= n) return;
  int beg = rowptr[g], end = rowptr[g + 1];
  float a0=0,a1=0,a2=0,a3=0,a4=0,a5=0,a6=0,a7=0;
  int j = beg;
  for (; j + 3 < end; j += 4) {
    int u0 = csr[j], u1 = csr[j + 1], u2 = csr[j + 2], u3 = csr[j + 3];
    uint4 v0 = *(const uint4*)(h + (size_t)u0 * HID + lane * 8);
    uint4 v1 = *(const uint4*)(h + (size_t)u1 * HID + lane * 8);
    uint4 v2 = *(const uint4*)(h + (size_t)u2 * HID + lane * 8);
    uint4 v3 = *(const uint4*)(h + (size_t)u3 * HID + lane * 8);
    a0 += (blo(v0.x) + blo(v1.x)) + (blo(v2.x) + blo(v3.x));
    a1 += (bhi(v0.x) + bhi(v1.x)) + (bhi(v2.x) + bhi(v3.x));
    a2 += (blo(v0.y) + blo(v1.y)) + (blo(v2.y) + blo(v3.y));
    a3 += (bhi(v0.y) + bhi(v1.y)) + (bhi(v2.y) + bhi(v3.y));
    a4 += (blo(v0.z) + blo(v1.z)) + (blo(v2.z) + blo(v3.z));
    a5 += (bhi(v0.z) + bhi(v1.z)) + (bhi(v2.z) + bhi(v3.z));
    a6 += (blo(v0.w) + blo(v1.w)) + (blo(v2.w) + blo(v3.w));
    a7 += (bhi(v0.w) + bhi(v1.w)) + (bhi(v2.w) + bhi(v3.w));
  }
  for (; j < end; ++j) {
    int u0 = csr[j];
    uint4 v0 = *(const uint4*)(h + (size_t)u0 * HID + lane * 8);
    a0 += blo(v0.x); a1 += bhi(v0.x); a2 += blo(v0.y); a3 += bhi(v0.y);
    a4 += blo(v0.z); a5 += bhi(v0.z); a6 += blo(v0.w); a7 += bhi(v0.w);
  }
  float r = (end > beg) ? 1.0f / (float)(end - beg) : 0.0f;
  uint4 o;
  o.x = pack2(a0 * r, a1 * r); o.y = pack2(a2 * r, a3 * r);
  o.z = pack2(a4 * r, a5 * r); o.w = pack2(a6 * r, a7 * r);
  *(uint4*)(outb + (size_t)g * HID + lane * 8) = o;
}

// ---------------- MFMA linear: C = A1@W1^T (+ A2@W2^T) + bias, bf16 in/out ----------

template <int NPARTS, bool STATS, bool ORELU>
__global__ __launch_bounds__(256) void mlin_kernel(
    const ushort* __restrict__ A1, const ushort* __restrict__ A2, int K,
    const ushort* __restrict__ W1, const ushort* __restrict__ W2,
    const float* __restrict__ bias, ushort* __restrict__ C,
    float* __restrict__ stats, int M) {
  __shared__ ushort As[128 * 32];
  __shared__ ushort Bs[128 * 32];
  const int tid = threadIdx.x;
  const int w = tid >> 6, l = tid & 63;
  const int mbase = blockIdx.x * 128;
  const int lm = l & 15, lq = l >> 4;
  floatx4 acc[2][8];
#pragma unroll
  for (int mt = 0; mt < 2; ++mt)
#pragma unroll
    for (int nt = 0; nt < 8; ++nt) {
      floatx4 z = {0.f, 0.f, 0.f, 0.f};
      acc[mt][nt] = z;
    }

  for (int part = 0; part < NPARTS; ++part) {
    const ushort* Ap = part ? A2 : A1;
    const ushort* Wp = part ? W2 : W1;
    for (int k0 = 0; k0 < K; k0 += 32) {
#pragma unroll
      for (int i = 0; i < 2; ++i) {
        int s = w * 2 + i;
        int rt = s * 16 + (l >> 2);
        int q = (l & 3) ^ ((rt >> 1) & 3);
        int grow = mbase + rt; grow = grow < M ? grow : M - 1;
        async_cp16(Ap + (size_t)grow * K + k0 + q * 8, &As[s * 512]);
        async_cp16(Wp + (size_t)rt * K + k0 + q * 8, &Bs[s * 512]);
      }
      __syncthreads();
      short8 b[8];
#pragma unroll
      for (int nt = 0; nt < 8; ++nt) {
        int row = nt * 16 + lm;
        int q = lq ^ ((row >> 1) & 3);
        b[nt] = *(const short8*)&Bs[row * 32 + q * 8];
      }
#pragma unroll
      for (int mt = 0; mt < 2; ++mt) {
        int row = (w * 2 + mt) * 16 + lm;
        int q = lq ^ ((row >> 1) & 3);
        short8 a = *(const short8*)&As[row * 32 + q * 8];
#pragma unroll
        for (int nt = 0; nt < 8; ++nt)
          acc[mt][nt] = __builtin_amdgcn_mfma_f32_16x16x32_bf16(a, b[nt], acc[mt][nt], 0, 0, 0);
      }
      __syncthreads();
    }
  }

  float ss[8], qq[8];
#pragma unroll
  for (int nt = 0; nt < 8; ++nt) { ss[nt] = 0.f; qq[nt] = 0.f; }
#pragma unroll
  for (int nt = 0; nt < 8; ++nt) {
    int col = nt * 16 + lm;
    float bv = bias[col];
#pragma unroll
    for (int mt = 0; mt < 2; ++mt) {
      int rbase = mbase + (w * 2 + mt) * 16 + lq * 4;
#pragma unroll
      for (int r = 0; r < 4; ++r) {
        int grow = rbase + r;
        if (grow < M) {
          float val = acc[mt][nt][r] + bv;
          if (ORELU) val = fmaxf(val, 0.f);
          C[(size_t)grow * 128 + col] = f2b(val);
          if (STATS) { ss[nt] += val; qq[nt] += val * val; }
        }
      }
    }
  }
  if (STATS) {
    float* sred = (float*)As;
    if (tid < 256) sred[tid] = 0.f;
    __syncthreads();
#pragma unroll
    for (int nt = 0; nt < 8; ++nt) {
      ss[nt] += __shfl_xor(ss[nt], 16); ss[nt] += __shfl_xor(ss[nt], 32);
      qq[nt] += __shfl_xor(qq[nt], 16); qq[nt] += __shfl_xor(qq[nt], 32);
    }
    if (lq == 0) {
#pragma unroll
      for (int nt = 0; nt < 8; ++nt) {
        int col = nt * 16 + lm;
        atomicAdd(&sred[col], ss[nt]);
        atomicAdd(&sred[128 + col], qq[nt]);
      }
    }
    __syncthreads();
    if (tid < 256) atomicAdd(&stats[tid], sred[tid]);
  }
}

// ---------------- BatchNorm apply (bf16 in-place, latency-optimized) ----------------

template <int ACT>  // 0=relu, 1=sigmoid
__global__ __launch_bounds__(256) void bnb_kernel(
    ushort* __restrict__ buf, const float* __restrict__ stats,
    const float* __restrict__ gamma, const float* __restrict__ beta, int n) {
  const int S = gridDim.x * 256;  // multiple of 16
  int idx = blockIdx.x * 256 + threadIdx.x;
  const int c0 = (idx & 15) * 8;
  const float inv_n = 1.0f / (float)n;
  float sc[8], sh[8];
#pragma unroll
  for (int d = 0; d < 8; ++d) {
    int c = c0 + d;
    float mu = stats[c] * inv_n;
    float var = stats[128 + c] * inv_n - mu * mu;
    float s = rsqrtf(var + 1e-5f) * gamma[c];
    sc[d] = s;
    sh[d] = beta[c] - mu * s;
  }
  const int n16 = n * 16;
  for (; idx < n16; idx += S) {
    uint4 v = ((const uint4*)buf)[idx];
    float x[8] = {blo(v.x), bhi(v.x), blo(v.y), bhi(v.y),
                  blo(v.z), bhi(v.z), blo(v.w), bhi(v.w)};
#pragma unroll
    for (int d = 0; d < 8; ++d) {
      float y = x[d] * sc[d] + sh[d];
      x[d] = (ACT == 0) ? fmaxf(y, 0.f) : 1.0f / (1.0f + expf(-y));
    }
    uint4 o;
    o.x = pack2(x[0], x[1]); o.y = pack2(x[2], x[3]);
    o.z = pack2(x[4], x[5]); o.w = pack2(x[6], x[7]);
    ((uint4*)buf)[idx] = o;
  }
}

// ---------------- classifier: MFMA GEMM + fused log_softmax ----------------

__global__ __launch_bounds__(256) void clsm_kernel(
    const ushort* __restrict__ A1, const ushort* __restrict__ A2,
    const ushort* __restrict__ Wcb, const float* __restrict__ bias,
    float* __restrict__ C, int M) {
  __shared__ ushort As[128 * 32];
  __shared__ ushort Bs[48 * 32];
  const int tid = threadIdx.x;
  const int w = tid >> 6, l = tid & 63;
  const int mbase = blockIdx.x * 128;
  const int lm = l & 15, lq = l >> 4;
  floatx4 acc[2][3];
#pragma unroll
  for (int mt = 0; mt < 2; ++mt)
#pragma unroll
    for (int nt = 0; nt < 3; ++nt) {
      floatx4 z = {0.f, 0.f, 0.f, 0.f};
      acc[mt][nt] = z;
    }

  for (int part = 0; part < 2; ++part) {
    const ushort* Ap = part ? A2 : A1;
    for (int k0 = 0; k0 < 128; k0 += 32) {
#pragma unroll
      for (int i = 0; i < 2; ++i) {
        int s = w * 2 + i;
        int rt = s * 16 + (l >> 2);
        int q = (l & 3) ^ ((rt >> 1) & 3);
        int grow = mbase + rt; grow = grow < M ? grow : M - 1;
        async_cp16(Ap + (size_t)grow * 128 + k0 + q * 8, &As[s * 512]);
      }
      if (w < 3) {
        int rt = w * 16 + (l >> 2);
        int q = (l & 3) ^ ((rt >> 1) & 3);
        async_cp16(Wcb + (size_t)rt * 256 + part * 128 + k0 + q * 8, &Bs[w * 512]);
      }
      __syncthreads();
      short8 b[3];
#pragma unroll
      for (int nt = 0; nt < 3; ++nt) {
        int row = nt * 16 + lm;
        int q = lq ^ ((row >> 1) & 3);
        b[nt] = *(const short8*)&Bs[row * 32 + q * 8];
      }
#pragma unroll
      for (int mt = 0; mt < 2; ++mt) {
        int row = (w * 2 + mt) * 16 + lm;
        int q = lq ^ ((row >> 1) & 3);
        short8 a = *(const short8*)&As[row * 32 + q * 8];
#pragma unroll
        for (int nt = 0; nt < 3; ++nt)
          acc[mt][nt] = __builtin_amdgcn_mfma_f32_16x16x32_bf16(a, b[nt], acc[mt][nt], 0, 0, 0);
      }
      __syncthreads();
    }
  }

  float b0v = bias[lm], b1v = bias[lm + 16];
  float b2v = (lm < 8) ? bias[lm + 32] : 0.f;
#pragma unroll
  for (int mt = 0; mt < 2; ++mt) {
#pragma unroll
    for (int r = 0; r < 4; ++r) {
      int grow = mbase + (w * 2 + mt) * 16 + lq * 4 + r;
      float v0 = acc[mt][0][r] + b0v;
      float v1 = acc[mt][1][r] + b1v;
      float v2 = (lm < 8) ? acc[mt][2][r] + b2v : -3.4e38f;
      float m = fmaxf(fmaxf(v0, v1), v2);
      m = fmaxf(m, __shfl_xor(m, 1)); m = fmaxf(m, __shfl_xor(m, 2));
      m = fmaxf(m, __shfl_xor(m, 4)); m = fmaxf(m, __shfl_xor(m, 8));
      float s = expf(v0 - m) + expf(v1 - m) + ((lm < 8) ? expf(v2 - m) : 0.f);
      s += __shfl_xor(s, 1); s += __shfl_xor(s, 2);
      s += __shfl_xor(s, 4); s += __shfl_xor(s, 8);
      float ls = m + logf(s);
      if (grow < M) {
        C[(size_t)grow * OUTC + lm] = v0 - ls;
        C[(size_t)grow * OUTC + lm + 16] = v1 - ls;
        if (lm < 8) C[(size_t)grow * OUTC + lm + 32] = v2 - ls;
      }
    }
  }
}

// ---------------- launch ----------------

extern "C" void kernel_launch(void* const* d_in, const int* in_sizes, int n_in,
                              void* d_out, int out_size, void* d_ws, size_t ws_size,
                              hipStream_t stream) {
  const float* x       = (const float*)d_in[0];
  const float* alpha   = (const float*)d_in[1];
  const int*   eidx    = (const int*)d_in[2];
  const float* sage_Wl = (const float*)d_in[3];
  const float* sage_bl = (const float*)d_in[4];
  const float* sage_Wr = (const float*)d_in[5];
  const float* sage_g  = (const float*)d_in[6];
  const float* sage_b  = (const float*)d_in[7];
  const float* W0 = (const float*)d_in[8];
  const float* b0 = (const float*)d_in[9];
  const float* W1 = (const float*)d_in[10];
  const float* b1 = (const float*)d_in[11];
  const float* W2 = (const float*)d_in[12];
  const float* b2 = (const float*)d_in[13];
  const float* mg = (const float*)d_in[14];
  const float* mb = (const float*)d_in[15];
  const float* Wc = (const float*)d_in[16];
  const float* bc = (const float*)d_in[17];
  const float* temp = (const float*)d_in[18];
  float* out = (float*)d_out;

  const int n = in_sizes[0] / HID;  // 100000
  const int e = in_sizes[2] / 2;    // 1600000
  const int* src = eidx;
  const int* tgt = eidx + e;

  const int nbk = (n + 511) >> 9;
  const int glen = nbk * PB;
  const int chunk = (e + PB - 1) / PB;

  // workspace layout: 4 N×128 bf16 regions (16B aligned)
  // B0 = xb (x bf16; SAGE L1 out)  B1 = [anb | ab] then SAGE L0/L2 out (hgnn)
  // B2 = agg buffer                 B3 = ebuf then hproto (proto chain, in-place)
  char* p = (char*)d_ws;
  ushort* B0 = (ushort*)p; p += (size_t)n * HID * 2;
  ushort* B1 = (ushort*)p; p += (size_t)n * HID * 2;
  ushort* B2 = (ushort*)p; p += (size_t)n * HID * 2;
  ushort* B3 = (ushort*)p; p += (size_t)n * HID * 2;
  ushort* wb     = (ushort*)p; p += (size_t)WTOT * 2;
  ushort* wcb    = (ushort*)p; p += (size_t)48 * 256 * 2;
  float* stats = (float*)p; p += 1024 * 4;
  int* rowptr = (int*)p; p += ((size_t)n + 1) * 4;
  int* csr    = (int*)p; p += (size_t)e * 4;
  int* G      = (int*)p; p += (size_t)glen * 4;
  int* Gs     = (int*)p; p += (size_t)glen * 4;
  int* blks   = (int*)p;
  ushort* xb   = B0;
  ushort* anb  = B1;                       // N*64
  ushort* ab   = B1 + (size_t)n * 64;      // N*64
  ushort* hgnn = B1;                       // SAGE L2 out (B1 dead by then)
  int*    ebuf = (int*)B3;                 // e*4 <= n*256
  ushort* hproto = B3;
  ushort* Wlb = wb, *Wrb = wb + 49152, *W0b = wb + 98304, *W1b = wb + 106496, *W2b = wb + 122880;

  const int T = 256;
  const int nb_scan = (glen + SCAN_ELEMS - 1) / SCAN_ELEMS;

  // ---- prep ----
  cvt_kernel<<<(n * (HID / 4) + T - 1) / T, T, 0, stream>>>(x, xb, n * (HID / 4));
  anorm2_kernel<<<(int)(((size_t)n * 16 + T - 1) / T), T, 0, stream>>>(alpha, ab, anb, n);
  cvtw_all_kernel<<<(WTOT / 4 + T - 1) / T, T, 0, stream>>>(sage_Wl, sage_Wr, W0, W1, W2, Wc,
                                                            wb, wcb, stats);

  // ---- bucketed CSR build (ebuf in B3) ----
  binA_kernel<<<PB, T, 0, stream>>>(tgt, G, e, chunk, nbk);
  scan1_kernel<<<nb_scan, SCAN_T, 0, stream>>>(G, Gs, blks, glen);
  scan2_kernel<<<1, SCAN_T, 0, stream>>>(blks, nb_scan);
  scan3g_kernel<<<(glen + T - 1) / T, T, 0, stream>>>(Gs, blks, glen);
  binB_kernel<<<PB, T, 0, stream>>>(src, tgt, Gs, ebuf, e, chunk, nbk);
  binC_kernel<<<nbk, T, 0, stream>>>(ebuf, Gs, rowptr, csr, n, e, nbk);

  const int gLin = (n + 127) / 128;
  const int gAgg = (int)(((size_t)n * 16 + T - 1) / T);
  const int gBn = 1024;

  // ---- fused L0 aggregate + gate (reads xb, anb; writes B2 + gate output) ----
  agg_gate_kernel<<<gAgg, T, 0, stream>>>(xb, anb, rowptr, csr, temp,
                                          out + (size_t)n * OUTC, B2, n);

  // ---- Proto MLP: ab -> B3 (in-place chain; ebuf dead after binC) ----
  mlin_kernel<1, true, false><<<gLin, T, 0, stream>>>(ab, nullptr, 64, W0b, nullptr,
                                                      b0, hproto, stats + 512, n);
  bnb_kernel<1><<<gBn, T, 0, stream>>>(hproto, stats + 512, mg, mb, n);
  mlin_kernel<1, true, false><<<gLin, T, 0, stream>>>(hproto, nullptr, 128, W1b, nullptr,
                                                      b1, hproto, stats + 768, n);
  bnb_kernel<1><<<gBn, T, 0, stream>>>(hproto, stats + 768, mg + HID, mb + HID, n);
  mlin_kernel<1, false, true><<<gLin, T, 0, stream>>>(hproto, nullptr, 128, W2b, nullptr,
                                                      b2, hproto, nullptr, n);

  // ---- SAGE L0: (B2 agg, B0 h) -> B1 (anb/ab dead) ----
  mlin_kernel<2, true, false><<<gLin, T, 0, stream>>>(B2, B0, 128, Wlb, Wrb,
                                                      sage_bl, B1, stats + 0, n);
  bnb_kernel<0><<<gBn, T, 0, stream>>>(B1, stats + 0, sage_g, sage_b, n);
  // ---- SAGE L1: agg(B1) -> B2; (B2, B1) -> B0 (xb dead) ----
  agg_b_kernel<<<gAgg, T, 0, stream>>>(B1, rowptr, csr, B2, n);
  mlin_kernel<2, true, false><<<gLin, T, 0, stream>>>(B2, B1, 128, Wlb + 16384, Wrb + 16384,
                                                      sage_bl + HID, B0, stats + 256, n);
  bnb_kernel<0><<<gBn, T, 0, stream>>>(B0, stats + 256, sage_g + HID, sage_b + HID, n);
  // ---- SAGE L2: agg(B0) -> B2; (B2, B0) -> B1 = hgnn (relu fused) ----
  agg_b_kernel<<<gAgg, T, 0, stream>>>(B0, rowptr, csr, B2, n);
  mlin_kernel<2, false, true><<<gLin, T, 0, stream>>>(B2, B0, 128, Wlb + 32768, Wrb + 32768,
                                                      sage_bl + 2 * HID, hgnn, nullptr, n);

  // ---- classifier (MFMA, log_softmax fused) ----
  clsm_kernel<<<gLin, T, 0, stream>>>(hgnn, hproto, wcb, bc, out, n);
}